// Round 1
// baseline (149.161 us; speedup 1.0000x reference)
//
#include <hip/hip_runtime.h>

#define Hn 128
#define Ln 2048
#define NBn 64
#define TB 64
#define PITCH 65   // 64 + 1 pad: reduce-phase banks = (t + k) % 32, 2-way aliasing (free)

// One block = one head, one wave of 64 lanes; lane n owns complex state n.
// Segmented recurrence: s = d[l] ? B*u_l : Lam*s + B*u_l  (exact emulation of
// the reference's associative-scan combine).
// Every TB steps: LDS transpose-reduce so lane t emits y[l0+t] coalesced.
__global__ __launch_bounds__(64) void ssm_scan_kernel(
    const float* __restrict__ u,
    const float* __restrict__ x_re, const float* __restrict__ x_im,
    const float* __restrict__ Lre,  const float* __restrict__ Lim,
    const float* __restrict__ Bre,  const float* __restrict__ Bim,
    const float* __restrict__ Cre,  const float* __restrict__ Cim,
    const float* __restrict__ Dv,   const int* __restrict__ dflag,
    float* __restrict__ out)
{
    __shared__ float g_s[TB * PITCH];
    __shared__ float u_s[TB];
    __shared__ int   d_s[TB];

    const int h  = blockIdx.x;
    const int n  = threadIdx.x;
    const int hn = h * NBn + n;

    const float lre  = Lre[hn], lim = Lim[hn];
    const float bre  = Bre[hn], bim = Bim[hn];
    const float c2re =  2.0f * Cre[hn];
    const float c2im = -2.0f * Cim[hn];
    const float Dh   = Dv[h];

    float sre = x_re[hn];
    float sim = x_im[hn];

    const float* urow = u + h * Ln;
    float*       yrow = out + h * Ln;

    // prefetch first batch of u/d into registers (off the serial chain)
    float u_next = urow[n];
    int   d_next = dflag[n];

    for (int l0 = 0; l0 < Ln; l0 += TB) {
        u_s[n] = u_next;
        d_s[n] = d_next;
        __syncthreads();
        // prefetch next batch while the scan below runs
        if (l0 + TB < Ln) {
            u_next = urow[l0 + TB + n];
            d_next = dflag[l0 + TB + n];
        }
        #pragma unroll
        for (int j = 0; j < TB; ++j) {
            const float ul  = u_s[j];
            const bool  rs  = d_s[j] != 0;
            const float bur = bre * ul;
            const float bui = bim * ul;
            const float tre = fmaf(lre, sre, fmaf(-lim, sim, bur));
            const float tim = fmaf(lre, sim, fmaf( lim, sre, bui));
            sre = rs ? bur : tre;
            sim = rs ? bui : tim;
            g_s[j * PITCH + n] = fmaf(c2re, sre, c2im * sim);
        }
        __syncthreads();
        // lane t reduces over all 64 states for timestep l0+t
        const float* row = g_s + n * PITCH;
        float a0 = 0.f, a1 = 0.f, a2 = 0.f, a3 = 0.f;
        #pragma unroll
        for (int k = 0; k < NBn; k += 4) {
            a0 += row[k + 0];
            a1 += row[k + 1];
            a2 += row[k + 2];
            a3 += row[k + 3];
        }
        yrow[l0 + n] = (a0 + a1) + (a2 + a3) + Dh * u_s[n];
        __syncthreads();
    }

    // final state, complex64 memory layout (interleaved re, im)
    float* xlast = out + Hn * Ln;
    xlast[2 * hn + 0] = sre;
    xlast[2 * hn + 1] = sim;
}

extern "C" void kernel_launch(void* const* d_in, const int* in_sizes, int n_in,
                              void* d_out, int out_size, void* d_ws, size_t ws_size,
                              hipStream_t stream) {
    const float* u    = (const float*)d_in[0];
    const float* x_re = (const float*)d_in[1];
    const float* x_im = (const float*)d_in[2];
    const float* Lre  = (const float*)d_in[3];
    const float* Lim  = (const float*)d_in[4];
    const float* Bre  = (const float*)d_in[5];
    const float* Bim  = (const float*)d_in[6];
    const float* Cre  = (const float*)d_in[7];
    const float* Cim  = (const float*)d_in[8];
    const float* Dv   = (const float*)d_in[9];
    const int*   dfl  = (const int*)d_in[10];
    float* out = (float*)d_out;

    ssm_scan_kernel<<<Hn, TB, 0, stream>>>(u, x_re, x_im, Lre, Lim,
                                           Bre, Bim, Cre, Cim, Dv, dfl, out);
}

// Round 2
// 90.997 us; speedup vs baseline: 1.6392x; 1.6392x over previous
//
#include <hip/hip_runtime.h>

#define Hn 128
#define Ln 2048
#define NBn 64
#define K 64          // chunk length (== lanes, for staging + transpose)
#define G 32          // chunks: G*K == Ln
#define PITCH 65      // 64+1 pad: reduce-phase 2-way bank aliasing is free (m136)

// ---------------------------------------------------------------------------
// Phase 1: per-(h,chunk) local scan with s_in = 0.
//   writes y_local (incl. D*u) to out, and chunk summary (A_c, b_c) to ws.
//   A_c = (any reset in chunk) ? 0 : Lam^64;  b_c = local end state.
// ---------------------------------------------------------------------------
__global__ __launch_bounds__(64) void phase1_local(
    const float* __restrict__ u,
    const float* __restrict__ Lre,  const float* __restrict__ Lim,
    const float* __restrict__ Bre,  const float* __restrict__ Bim,
    const float* __restrict__ Cre,  const float* __restrict__ Cim,
    const float* __restrict__ Dv,   const int* __restrict__ dflag,
    float* __restrict__ out,
    float* __restrict__ Acr, float* __restrict__ Aci,
    float* __restrict__ Bcr, float* __restrict__ Bci)
{
    __shared__ float g_s[K * PITCH];
    __shared__ float u_s[K];
    __shared__ int   d_s[K];

    const int g = blockIdx.x, h = blockIdx.y, n = threadIdx.x;
    const int hn = h * NBn + n;
    const int l0 = g * K;

    const float lre = Lre[hn], lim = Lim[hn];
    const float bre = Bre[hn], bim = Bim[hn];
    const float c2re =  2.0f * Cre[hn];
    const float c2im = -2.0f * Cim[hn];
    const float Dh   = Dv[h];

    u_s[n] = u[h * Ln + l0 + n];
    const int dn = dflag[l0 + n];
    d_s[n] = dn;
    __syncthreads();

    float zre = 0.f, zim = 0.f;
    #pragma unroll
    for (int k = 0; k < K; ++k) {
        const float ul = u_s[k];
        const bool  rs = d_s[k] != 0;
        const float bur = bre * ul;
        const float bui = bim * ul;
        const float tre = fmaf(lre, zre, fmaf(-lim, zim, bur));
        const float tim = fmaf(lre, zim, fmaf( lim, zre, bui));
        zre = rs ? bur : tre;
        zim = rs ? bui : tim;
        g_s[k * PITCH + n] = fmaf(c2re, zre, c2im * zim);
    }
    __syncthreads();

    // lane t reduces over the 64 states for timestep l0+t (coalesced y write)
    const float* row = g_s + n * PITCH;
    float a0 = 0.f, a1 = 0.f, a2 = 0.f, a3 = 0.f;
    #pragma unroll
    for (int k = 0; k < NBn; k += 4) {
        a0 += row[k + 0]; a1 += row[k + 1];
        a2 += row[k + 2]; a3 += row[k + 3];
    }
    out[h * Ln + l0 + n] = (a0 + a1) + (a2 + a3) + Dh * u_s[n];

    // chunk summary
    const unsigned long long bal = __ballot(dn != 0);
    float pr = lre, pi = lim;            // Lam^64 via 6 squarings
    #pragma unroll
    for (int it = 0; it < 6; ++it) {
        const float nr = pr * pr - pi * pi;
        const float ni = 2.f * pr * pi;
        pr = nr; pi = ni;
    }
    if (bal) { pr = 0.f; pi = 0.f; }     // any reset kills s_in propagation
    const int idx = (h * G + g) * NBn + n;
    Acr[idx] = pr;  Aci[idx] = pi;
    Bcr[idx] = zre; Bci[idx] = zim;
}

// ---------------------------------------------------------------------------
// Phase 2: per-head serial combine over chunks; stores each chunk's INCOMING
// state over (Bcr,Bci); writes final state (interleaved complex64) to out.
// ---------------------------------------------------------------------------
__global__ __launch_bounds__(64) void phase2_combine(
    const float* __restrict__ x_re, const float* __restrict__ x_im,
    const float* __restrict__ Acr,  const float* __restrict__ Aci,
    float* __restrict__ Bcr,        float* __restrict__ Bci,
    float* __restrict__ out)
{
    const int h = blockIdx.x, n = threadIdx.x;
    const int hn = h * NBn + n;
    float sre = x_re[hn], sim = x_im[hn];
    #pragma unroll
    for (int g = 0; g < G; ++g) {
        const int idx = (h * G + g) * NBn + n;
        const float ar = Acr[idx], ai = Aci[idx];
        const float br = Bcr[idx], bi = Bci[idx];
        Bcr[idx] = sre;            // incoming state for chunk g
        Bci[idx] = sim;
        const float nr = fmaf(ar, sre, fmaf(-ai, sim, br));
        const float ni = fmaf(ar, sim, fmaf( ai, sre, bi));
        sre = nr; sim = ni;
    }
    float* xlast = out + Hn * Ln;
    xlast[2 * hn + 0] = sre;
    xlast[2 * hn + 1] = sim;
}

// ---------------------------------------------------------------------------
// Phase 3: per-(h,chunk) correction: y[l0+k] += 2*Re(sum_n C_n Lam_n^{k+1} s_in_n)
// masked to zero from the first reset in the chunk onward.
// ---------------------------------------------------------------------------
__global__ __launch_bounds__(64) void phase3_fixup(
    const float* __restrict__ Lre, const float* __restrict__ Lim,
    const float* __restrict__ Cre, const float* __restrict__ Cim,
    const int* __restrict__ dflag,
    const float* __restrict__ Scr, const float* __restrict__ Sci,
    float* __restrict__ out)
{
    __shared__ float g_s[K * PITCH];

    const int g = blockIdx.x, h = blockIdx.y, n = threadIdx.x;
    const int hn = h * NBn + n;
    const int l0 = g * K;
    const int idx = (h * G + g) * NBn + n;

    const float sr = Scr[idx], si = Sci[idx];
    const float cr = Cre[hn],  ci = Cim[hn];
    const float lre = Lre[hn], lim = Lim[hn];

    float tr = cr * sr - ci * si;      // C * s_in  (Lam^0)
    float ti = cr * si + ci * sr;

    const int dn = dflag[l0 + n];
    const unsigned long long bal = __ballot(dn != 0);
    const int kr = bal ? (__ffsll(bal) - 1) : K;   // first reset local index

    #pragma unroll
    for (int k = 0; k < K; ++k) {
        const float nr = fmaf(lre, tr, -lim * ti); // t *= Lam  -> Lam^{k+1}
        const float ni = fmaf(lre, ti,  lim * tr);
        tr = nr; ti = ni;
        g_s[k * PITCH + n] = tr;
    }
    __syncthreads();

    const float* row = g_s + n * PITCH;
    float a0 = 0.f, a1 = 0.f, a2 = 0.f, a3 = 0.f;
    #pragma unroll
    for (int k = 0; k < NBn; k += 4) {
        a0 += row[k + 0]; a1 += row[k + 1];
        a2 += row[k + 2]; a3 += row[k + 3];
    }
    if (n < kr)
        out[h * Ln + l0 + n] += 2.f * ((a0 + a1) + (a2 + a3));
}

extern "C" void kernel_launch(void* const* d_in, const int* in_sizes, int n_in,
                              void* d_out, int out_size, void* d_ws, size_t ws_size,
                              hipStream_t stream) {
    const float* u    = (const float*)d_in[0];
    const float* x_re = (const float*)d_in[1];
    const float* x_im = (const float*)d_in[2];
    const float* Lre  = (const float*)d_in[3];
    const float* Lim  = (const float*)d_in[4];
    const float* Bre  = (const float*)d_in[5];
    const float* Bim  = (const float*)d_in[6];
    const float* Cre  = (const float*)d_in[7];
    const float* Cim  = (const float*)d_in[8];
    const float* Dv   = (const float*)d_in[9];
    const int*   dfl  = (const int*)d_in[10];
    float* out = (float*)d_out;

    const int HGN = Hn * G * NBn;          // 262144 floats = 1 MB per buffer
    float* Acr = (float*)d_ws;
    float* Aci = Acr + HGN;
    float* Bcr = Aci + HGN;                // becomes s_in_re after phase 2
    float* Bci = Bcr + HGN;                // becomes s_in_im after phase 2

    dim3 gridA(G, Hn);
    phase1_local<<<gridA, 64, 0, stream>>>(u, Lre, Lim, Bre, Bim, Cre, Cim,
                                           Dv, dfl, out, Acr, Aci, Bcr, Bci);
    phase2_combine<<<Hn, 64, 0, stream>>>(x_re, x_im, Acr, Aci, Bcr, Bci, out);
    phase3_fixup<<<gridA, 64, 0, stream>>>(Lre, Lim, Cre, Cim, dfl,
                                           Bcr, Bci, out);
}